// Round 11
// baseline (513.294 us; speedup 1.0000x reference)
//
#include <hip/hip_runtime.h>
#include <hip/hip_bf16.h>
#include <hip/hip_cooperative_groups.h>

namespace cg = cooperative_groups;

// EdgeConv: N=16384 points, C=64, D=64, K=16 neighbors. All I/O fp32.
// R11: ONE cooperative dispatch (was 6 dispatches; ~8us/dispatch boundary):
//   S0: zero counts/ctrs || prep (v=x@(W1a-W1b)+b1 -> out, u=x@W1b -> ubuf bf16)
//   S1: grid count   S2: scan (block 0)   S3: scatter
//   S4: grid KNN -- queries in SORTED order via atomic batch-stealing;
//       DPP wave-scan (row_shr+row_bcast, ~25cyc) replaces shfl_up chain (~180)
//   S5: edge -- tile-stealing; h=relu(v_i+u_j) -> MFMA @W2 -> max_k + b2
// Numerics byte-identical to R10 (ref-formula distance, monotone u64 keys,
// bitonic warm start, tau+1e-4 shell termination).

#define NPTS 16384
#define CH 64
#define GLO  (-4.5f)
#define GH   0.28125f          // 9/32
#define INVH 3.5555555556f     // 32/9
#define GDIM 32
#define GCELLS (GDIM * GDIM * GDIM)
#define NTILES (NPTS / 8)
#define SENT 0xFF800000FFFFFFFFULL
#define NB 4

typedef __attribute__((ext_vector_type(8))) short short8;
typedef __attribute__((ext_vector_type(4))) float floatx4;

__device__ __forceinline__ unsigned short f2bf(float f) {
    unsigned u = __float_as_uint(f);
    u += 0x7FFFu + ((u >> 16) & 1u);   // RNE
    return (unsigned short)(u >> 16);
}
__device__ __forceinline__ float bf2f(unsigned short u) {
    return __uint_as_float(((unsigned)u) << 16);
}
__device__ __forceinline__ unsigned long long dpp_shr1_u64(unsigned long long x) {
    int lo = (int)(unsigned)(x & 0xFFFFFFFFULL);
    int hi = (int)(unsigned)(x >> 32);
    lo = __builtin_amdgcn_update_dpp(0, lo, 0x111, 0xF, 0xF, false);
    hi = __builtin_amdgcn_update_dpp(0, hi, 0x111, 0xF, 0xF, false);
    return (((unsigned long long)(unsigned)hi) << 32) | (unsigned)lo;
}
// wave64 inclusive scan via DPP (canonical GCN sequence, ~6 VALU adds)
__device__ __forceinline__ unsigned wave_iscan(unsigned x) {
    x += (unsigned)__builtin_amdgcn_update_dpp(0, (int)x, 0x111, 0xF, 0xF, true);
    x += (unsigned)__builtin_amdgcn_update_dpp(0, (int)x, 0x112, 0xF, 0xF, true);
    x += (unsigned)__builtin_amdgcn_update_dpp(0, (int)x, 0x114, 0xF, 0xF, true);
    x += (unsigned)__builtin_amdgcn_update_dpp(0, (int)x, 0x118, 0xF, 0xF, true);
    x += (unsigned)__builtin_amdgcn_update_dpp(0, (int)x, 0x142, 0xA, 0xF, true);
    x += (unsigned)__builtin_amdgcn_update_dpp(0, (int)x, 0x143, 0xC, 0xF, true);
    return x;
}
__device__ __forceinline__ int cell_of(float x, float y, float z) {
    int cx = (int)floorf((x - GLO) * INVH);
    int cy = (int)floorf((y - GLO) * INVH);
    int cz = (int)floorf((z - GLO) * INVH);
    cx = min(max(cx, 0), GDIM - 1);
    cy = min(max(cy, 0), GDIM - 1);
    cz = min(max(cz, 0), GDIM - 1);
    return (cz * GDIM + cy) * GDIM + cx;
}

// LDS union: prep {Wct 18432 | Abuf 9216}, edge {h 18432 | W2t 9216 | tile 4},
// knn {ex 1024 | st 1024}, scan {1024}
#define SMEM_BYTES 27664

__global__ __launch_bounds__(256, 4) void mega_kernel(
        const float* __restrict__ pos, const float* __restrict__ x,
        const float* __restrict__ W1, const float* __restrict__ b1,
        const float* __restrict__ W2, const float* __restrict__ b2,
        float* __restrict__ out, int* __restrict__ counts,
        int* __restrict__ starts, int* __restrict__ cursor,
        float4* __restrict__ spos, unsigned short* __restrict__ sidx,
        unsigned short* __restrict__ knn, unsigned short* __restrict__ ubuf,
        int* __restrict__ ctrs) {
    __shared__ alignas(16) char smem[SMEM_BYTES];
    cg::grid_group grid = cg::this_grid();

    const int t     = threadIdx.x;
    const int lane  = t & 63;
    const int w     = t >> 6;
    const int gsize = gridDim.x * 256;
    const int gtid  = blockIdx.x * 256 + t;

    // ================= S0: zero counts/ctrs + prep =================
    for (int c = gtid; c < GCELLS; c += gsize) counts[c] = 0;
    if (gtid == 0) { ctrs[0] = 0; ctrs[1] = 0; }

    {
        unsigned short* Wct  = (unsigned short*)smem;            // [128][72]
        unsigned short* Abuf = (unsigned short*)(smem + 18432);  // [64][72]
        const int m16 = lane & 15;
        const int q   = lane >> 4;
        if (blockIdx.x < NPTS / 64) {
            {   // Wct[n][k]: n<64 -> (W1a-W1b) col, else W1b col (coalesced)
                const int n  = t & 127;
                const int ks = (t >> 7) * 32;
#pragma unroll
                for (int i = 0; i < 32; ++i) {
                    const int k = ks + i;
                    float val;
                    if (n < 64) val = W1[k * 64 + n] - W1[(64 + k) * 64 + n];
                    else        val = W1[(64 + k) * 64 + (n - 64)];
                    Wct[n * 72 + k] = f2bf(val);
                }
            }
            for (int tile = blockIdx.x; tile < NPTS / 64; tile += gridDim.x) {
                __syncthreads();
                {
                    const int col = t & 63;
#pragma unroll
                    for (int i = 0; i < 16; ++i) {
                        const int r2 = (t >> 6) + 4 * i;
                        const int gp = tile * 64 + r2;
                        Abuf[r2 * 72 + col] = f2bf(x[(size_t)gp * CH + col]);
                    }
                }
                __syncthreads();
                floatx4 acc[8];
#pragma unroll
                for (int nt = 0; nt < 8; ++nt) acc[nt] = (floatx4){0.f, 0.f, 0.f, 0.f};
#pragma unroll
                for (int kk = 0; kk < 64; kk += 32) {
                    const short8 a = *(const short8*)(Abuf + (w * 16 + m16) * 72 + kk + q * 8);
#pragma unroll
                    for (int nt = 0; nt < 8; ++nt) {
                        const short8 b = *(const short8*)(Wct + (nt * 16 + m16) * 72 + kk + q * 8);
                        acc[nt] = __builtin_amdgcn_mfma_f32_16x16x32_bf16(a, b, acc[nt], 0, 0, 0);
                    }
                }
#pragma unroll
                for (int nt = 0; nt < 8; ++nt) {
                    const int n = nt * 16 + m16;
#pragma unroll
                    for (int r = 0; r < 4; ++r) {
                        const int gp = tile * 64 + w * 16 + q * 4 + r;
                        if (n < 64) out[(size_t)gp * CH + n] = acc[nt][r] + b1[n];
                        else        ubuf[(size_t)gp * CH + (n - 64)] = f2bf(acc[nt][r]);
                    }
                }
            }
        }
    }
    grid.sync();

    // ================= S1: count =================
    for (int i = gtid; i < NPTS; i += gsize)
        atomicAdd(&counts[cell_of(pos[i * 3], pos[i * 3 + 1], pos[i * 3 + 2])], 1);
    grid.sync();

    // ================= S2: scan (block 0; starts[GCELLS]=NPTS sentinel) ====
    if (blockIdx.x == 0) {
        int* slds = (int*)smem;
        const int4* c4 = (const int4*)counts + t * 32;
        int sum = 0;
#pragma unroll 8
        for (int i = 0; i < 32; ++i) {
            const int4 u = c4[i];
            sum += u.x + u.y + u.z + u.w;
        }
        slds[t] = sum;
        __syncthreads();
        for (int off = 1; off < 256; off <<= 1) {
            int vv = 0;
            if (t >= off) vv = slds[t - off];
            __syncthreads();
            slds[t] += vv;
            __syncthreads();
        }
        int pre = (t == 0) ? 0 : slds[t - 1];
        int4* s4 = (int4*)starts + t * 32;
        int4* u4 = (int4*)cursor + t * 32;
#pragma unroll 8
        for (int i = 0; i < 32; ++i) {
            const int4 u = c4[i];
            int4 o;
            o.x = pre; pre += u.x;
            o.y = pre; pre += u.y;
            o.z = pre; pre += u.z;
            o.w = pre; pre += u.w;
            s4[i] = o;
            u4[i] = o;
        }
        if (t == 255) starts[GCELLS] = pre;
    }
    grid.sync();

    // ================= S3: scatter (sorted-by-cell array) =================
    for (int i = gtid; i < NPTS; i += gsize) {
        const float a = pos[i * 3], b = pos[i * 3 + 1], c = pos[i * 3 + 2];
        const int dst = atomicAdd(&cursor[cell_of(a, b, c)], 1);
        spos[dst] = make_float4(a, b, c, a * a + b * b + c * c);
        sidx[dst] = (unsigned short)i;
    }
    grid.sync();

    // ================= S4: grid KNN (sorted order, batch-stealing) ========
    {
        int* lds_ex = (int*)smem + w * 64;          // per-wave 64 ints
        int* lds_st = (int*)(smem + 1024) + w * 64;
        while (true) {
            int sq0 = 0;
            if (lane == 0) sq0 = atomicAdd(&ctrs[0], 4);
            sq0 = __shfl(sq0, 0);
            if (sq0 >= NPTS) break;
            for (int qi = 0; qi < 4; ++qi) {
                const int sq = sq0 + qi;
                const float4 qv = spos[sq];
                const float qx = qv.x, qy = qv.y, qz = qv.z, sqi = qv.w;
                const int qrow = (int)sidx[sq];   // original index (output row)
                const int cix = min(max((int)floorf((qx - GLO) * INVH), 0), GDIM - 1);
                const int ciy = min(max((int)floorf((qy - GLO) * INVH), 0), GDIM - 1);
                const int ciz = min(max((int)floorf((qz - GLO) * INVH), 0), GDIM - 1);

                unsigned long long list = SENT;
                float tau = __uint_as_float(0x7F800000u);
                bool first = true;
                int pax = 1, pbx = 0, pay = 1, pby = 0, paz = 1, pbz = 0;

                for (int s = 1; s < GDIM + 1; ++s) {
                    const int ax = max(cix - s, 0), bx = min(cix + s, GDIM - 1);
                    const int ay = max(ciy - s, 0), by = min(ciy + s, GDIM - 1);
                    const int az = max(ciz - s, 0), bz = min(ciz + s, GDIM - 1);
                    const int dy = by - ay + 1, dz = bz - az + 1;
                    const int npair = dy * dz;
                    const float invdy = 1.0f / (float)dy;

                    for (int pb = 0; pb < npair; pb += 64) {
                        const int pair = pb + lane;
                        int stA = 0, lenA = 0, stB = 0, lenB = 0;
                        if (pair < npair) {
                            const int czo = (int)(((float)pair + 0.5f) * invdy);
                            const int cyo = pair - czo * dy;
                            const int cy = ay + cyo, cz = az + czo;
                            const int rowb = (cz * GDIM + cy) * GDIM;
                            const bool inner = cy >= pay && cy <= pby &&
                                               cz >= paz && cz <= pbz;
                            const int bA = inner ? (pax - 1) : bx;
                            if (bA >= ax) {
                                stA  = starts[rowb + ax];
                                lenA = starts[rowb + bA + 1] - stA;
                            }
                            if (inner) {
                                const int aB = pbx + 1;
                                if (bx >= aB) {
                                    stB  = starts[rowb + aB];
                                    lenB = starts[rowb + bx + 1] - stB;
                                }
                            }
                        }
#pragma unroll
                        for (int setsel = 0; setsel < 2; ++setsel) {
                            const int st  = setsel ? stB  : stA;
                            const int len = setsel ? lenB : lenA;
                            if (__ballot(len > 0) == 0ULL) continue;
                            const unsigned pfx = wave_iscan((unsigned)len);  // DPP scan
                            const int T  = __builtin_amdgcn_readlane((int)pfx, 63);
                            lds_ex[lane] = (int)pfx - len;
                            lds_st[lane] = st;

                            for (int b0 = 0; b0 < T; b0 += 64 * NB) {
                                float4 pts[NB];
                                int    jor[NB];
                                bool   act[NB];
                                bool   live[NB];
#pragma unroll
                                for (int nb = 0; nb < NB; ++nb) {
                                    const int bb = b0 + nb * 64;
                                    live[nb] = bb < T;
                                    act[nb] = false;
                                    if (live[nb]) {
                                        const int p = bb + lane;
                                        int j = 0;
#pragma unroll
                                        for (int stp = 32; stp >= 1; stp >>= 1) {
                                            const int m = j + stp;
                                            if (lds_ex[m] <= p) j = m;
                                        }
                                        int idx = lds_st[j] + (p - lds_ex[j]);
                                        idx = min(idx, NPTS - 1);
                                        act[nb] = p < T;
                                        pts[nb] = spos[idx];
                                        jor[nb] = (int)sidx[idx];
                                    }
                                }
#pragma unroll
                                for (int nb = 0; nb < NB; ++nb) {
                                    if (!live[nb]) continue;
                                    const float dot = fmaf(qx, pts[nb].x,
                                                     fmaf(qy, pts[nb].y, qz * pts[nb].z));
                                    const float d = fmaf(-2.0f, dot, sqi + pts[nb].w);

                                    if (first) {
                                        first = false;
                                        unsigned kd = __float_as_uint(d);
                                        kd = ((int)kd < 0) ? ~kd : (kd | 0x80000000u);
                                        unsigned long long key =
                                            (((unsigned long long)kd) << 32) |
                                            (unsigned)jor[nb];
                                        if (!(act[nb] && jor[nb] != qrow)) key = SENT;
#pragma unroll
                                        for (int k = 2; k <= 64; k <<= 1) {
#pragma unroll
                                            for (int jj = k >> 1; jj >= 1; jj >>= 1) {
                                                const unsigned long long o =
                                                    __shfl_xor(key, jj);
                                                const bool takeMin =
                                                    (((lane & k) == 0) == ((lane & jj) == 0));
                                                const unsigned long long mn = (key < o) ? key : o;
                                                const unsigned long long mx = (key < o) ? o : key;
                                                key = takeMin ? mn : mx;
                                            }
                                        }
                                        list = key;
                                        const unsigned thi = (unsigned)
                                            __builtin_amdgcn_readlane(
                                                (int)(unsigned)(list >> 32), 15);
                                        const unsigned fb = (thi >= 0x80000000u)
                                            ? (thi & 0x7FFFFFFFu) : ~thi;
                                        tau = __uint_as_float(fb);
                                        continue;
                                    }

                                    const bool cand = act[nb] && (jor[nb] != qrow) &&
                                                      (d <= tau);
                                    unsigned long long mask = __ballot(cand);
                                    if (mask) {
                                        unsigned kd = __float_as_uint(d);
                                        kd = ((int)kd < 0) ? ~kd : (kd | 0x80000000u);
                                        do {
                                            const int src = __ffsll(mask) - 1;
                                            mask &= mask - 1;
                                            const unsigned slo = (unsigned)
                                                __builtin_amdgcn_readlane(jor[nb], src);
                                            const unsigned shi = (unsigned)
                                                __builtin_amdgcn_readlane((int)kd, src);
                                            const unsigned long long v =
                                                (((unsigned long long)shi) << 32) | slo;
                                            const unsigned long long prev = dpp_shr1_u64(list);
                                            const unsigned long long lr = list;
                                            list = (lr < v) ? lr : ((prev < v) ? v : prev);
                                        } while (mask);
                                        const unsigned thi = (unsigned)
                                            __builtin_amdgcn_readlane(
                                                (int)(unsigned)(list >> 32), 15);
                                        const unsigned fb = (thi >= 0x80000000u)
                                            ? (thi & 0x7FFFFFFFu) : ~thi;
                                        tau = __uint_as_float(fb);
                                    }
                                }
                            }
                        }
                    }

                    const float BIG = 1e30f;
                    float dout = BIG;
                    if (ax > 0)        dout = fminf(dout, qx - (GLO + ax * GH));
                    if (bx < GDIM - 1) dout = fminf(dout, (GLO + (bx + 1) * GH) - qx);
                    if (ay > 0)        dout = fminf(dout, qy - (GLO + ay * GH));
                    if (by < GDIM - 1) dout = fminf(dout, (GLO + (by + 1) * GH) - qy);
                    if (az > 0)        dout = fminf(dout, qz - (GLO + az * GH));
                    if (bz < GDIM - 1) dout = fminf(dout, (GLO + (bz + 1) * GH) - qz);
                    if (dout * dout > tau + 1e-4f) break;
                    if (ax == 0 && bx == GDIM - 1 && ay == 0 && by == GDIM - 1 &&
                        az == 0 && bz == GDIM - 1) break;
                    pax = ax; pbx = bx; pay = ay; pby = by; paz = az; pbz = bz;
                }

                if (lane < 16)
                    knn[qrow * 16 + lane] = (unsigned short)(list & 0xFFFFULL);
            }
        }
    }
    grid.sync();

    // ================= S5: edge (tile stealing) =================
    {
        unsigned short* h   = (unsigned short*)smem;            // [128][72]
        unsigned short* W2t = (unsigned short*)(smem + 18432);  // [64][72]
        int* sm_tile = (int*)(smem + 27648);
        const int m16 = lane & 15;
        const int q   = lane >> 4;
        {   // W2^T -> bf16 (tile-independent)
            const int n = t & 63;
            const int kb = (t >> 6) * 16;
#pragma unroll
            for (int i = 0; i < 16; ++i) {
                const int k = kb + i;
                W2t[n * 72 + k] = f2bf(W2[k * 64 + n]);
            }
        }
        __syncthreads();
        while (true) {
            if (t == 0) *sm_tile = atomicAdd(&ctrs[1], 1);
            __syncthreads();
            const int tile = *sm_tile;
            if (tile >= NTILES) break;
            {
                const int k = t >> 4;
                const int c = t & 15;
#pragma unroll
                for (int i = 0; i < 8; ++i) {
                    const int gn = tile * 8 + i;
                    const int gj = (int)knn[gn * 16 + k];
                    const float4  vv = ((const float4*)(out + (size_t)gn * CH))[c];
                    const ushort4 uu = ((const ushort4*)(ubuf + (size_t)gj * CH))[c];
                    ushort4 hv;
                    hv.x = f2bf(fmaxf(vv.x + bf2f(uu.x), 0.f));
                    hv.y = f2bf(fmaxf(vv.y + bf2f(uu.y), 0.f));
                    hv.z = f2bf(fmaxf(vv.z + bf2f(uu.z), 0.f));
                    hv.w = f2bf(fmaxf(vv.w + bf2f(uu.w), 0.f));
                    const int r2 = i * 16 + k;
                    *(ushort4*)(h + r2 * 72 + c * 4) = hv;
                }
            }
            __syncthreads();
            floatx4 acc[2][4];
#pragma unroll
            for (int i = 0; i < 2; ++i)
#pragma unroll
                for (int nt = 0; nt < 4; ++nt) acc[i][nt] = (floatx4){0.f, 0.f, 0.f, 0.f};
#pragma unroll
            for (int kk = 0; kk < 64; kk += 32) {
                const short8 a0 = *(const short8*)(h + ((w * 2 + 0) * 16 + m16) * 72 + kk + q * 8);
                const short8 a1 = *(const short8*)(h + ((w * 2 + 1) * 16 + m16) * 72 + kk + q * 8);
#pragma unroll
                for (int nt = 0; nt < 4; ++nt) {
                    const short8 b = *(const short8*)(W2t + (nt * 16 + m16) * 72 + kk + q * 8);
                    acc[0][nt] = __builtin_amdgcn_mfma_f32_16x16x32_bf16(a0, b, acc[0][nt], 0, 0, 0);
                    acc[1][nt] = __builtin_amdgcn_mfma_f32_16x16x32_bf16(a1, b, acc[1][nt], 0, 0, 0);
                }
            }
#pragma unroll
            for (int i = 0; i < 2; ++i) {
                const int mt = w * 2 + i;
                const int gn = tile * 8 + mt;
#pragma unroll
                for (int nt = 0; nt < 4; ++nt) {
                    float m0 = fmaxf(fmaxf(acc[i][nt][0], acc[i][nt][1]),
                                     fmaxf(acc[i][nt][2], acc[i][nt][3]));
                    m0 = fmaxf(m0, __shfl_xor(m0, 16));
                    m0 = fmaxf(m0, __shfl_xor(m0, 32));
                    if (lane < 16)
                        out[(size_t)gn * CH + nt * 16 + lane] = m0 + b2[nt * 16 + lane];
                }
            }
            __syncthreads();   // protect h + sm_tile before next iteration
        }
    }
}

extern "C" void kernel_launch(void* const* d_in, const int* in_sizes, int n_in,
                              void* d_out, int out_size, void* d_ws, size_t ws_size,
                              hipStream_t stream) {
    const float* x   = (const float*)d_in[0];
    const float* pos = (const float*)d_in[1];
    const float* W1  = (const float*)d_in[2];
    const float* b1  = (const float*)d_in[3];
    const float* W2  = (const float*)d_in[4];
    const float* b2  = (const float*)d_in[5];
    float* out = (float*)d_out;

    char* ws = (char*)d_ws;
    unsigned short* knn  = (unsigned short*)ws;                    // 512 KB
    unsigned short* ubuf = (unsigned short*)(ws + 524288);         // 2 MB
    int*    counts = (int*)(ws + 2621440);                         // 128 KB
    int*    starts = (int*)(ws + 2752512);                         // 128 KB + sentinel
    int*    cursor = (int*)(ws + 2883600);                         // 128 KB
    float4* spos   = (float4*)(ws + 3014672);                      // 256 KB
    unsigned short* sidx = (unsigned short*)(ws + 3276816);        // 32 KB
    int*    ctrs   = (int*)(ws + 3309584);                         // 16 B

    int occ = 0;
    hipOccupancyMaxActiveBlocksPerMultiprocessor(&occ, mega_kernel, 256, 0);
    if (occ < 1) occ = 1;
    int gridN = occ * 256;            // 256 CUs on MI355X
    if (gridN > 2048) gridN = 2048;

    void* args[] = {(void*)&pos, (void*)&x, (void*)&W1, (void*)&b1,
                    (void*)&W2, (void*)&b2, (void*)&out, (void*)&counts,
                    (void*)&starts, (void*)&cursor, (void*)&spos, (void*)&sidx,
                    (void*)&knn, (void*)&ubuf, (void*)&ctrs};
    hipLaunchCooperativeKernel((const void*)mega_kernel, dim3(gridN), dim3(256),
                               args, 0, stream);
}

// Round 12
// 151.229 us; speedup vs baseline: 3.3942x; 3.3942x over previous
//
#include <hip/hip_runtime.h>
#include <hip/hip_bf16.h>

// EdgeConv: N=16384 points, C=64, D=64, K=16 neighbors. All I/O fp32.
// Pipeline (6 graph nodes, R10 skeleton -- R11's cooperative mega-kernel
// regressed 3.5x: grid.sync() on 8 non-coherent XCDs ~ 100us/barrier):
//   memset(counts) -> [count | prep fused] -> scan -> scatter -> knn -> edge
// R12 knn: append-and-flush selection (ballot-rank LDS append ~2 ops/event;
// tau refreshed at flushes: bitonic64 sort + bitonic32 merge vs running
// top-16) replaces the serial per-event insert chain (~120 trips x ~12
// cross-lane ops). Exact: flush keeps top-16 of (top16 U buffer). Queries in
// sorted spatial order (blockIdx = sorted idx). DPP wave-scan for run prefix.
// Distance/keys/termination byte-identical to R10.

#define NPTS 16384
#define CH 64

#define GLO  (-4.5f)
#define GH   0.28125f          // 9/32
#define INVH 3.5555555556f     // 32/9
#define GDIM 32
#define GCELLS (GDIM * GDIM * GDIM)

typedef __attribute__((ext_vector_type(8))) short short8;
typedef __attribute__((ext_vector_type(4))) float floatx4;

__device__ __forceinline__ unsigned short f2bf(float f) {
    unsigned u = __float_as_uint(f);
    u += 0x7FFFu + ((u >> 16) & 1u);   // RNE
    return (unsigned short)(u >> 16);
}
__device__ __forceinline__ float bf2f(unsigned short u) {
    return __uint_as_float(((unsigned)u) << 16);
}
// wave64 inclusive scan via DPP (validated in passing R11)
__device__ __forceinline__ unsigned wave_iscan(unsigned x) {
    x += (unsigned)__builtin_amdgcn_update_dpp(0, (int)x, 0x111, 0xF, 0xF, true);
    x += (unsigned)__builtin_amdgcn_update_dpp(0, (int)x, 0x112, 0xF, 0xF, true);
    x += (unsigned)__builtin_amdgcn_update_dpp(0, (int)x, 0x114, 0xF, 0xF, true);
    x += (unsigned)__builtin_amdgcn_update_dpp(0, (int)x, 0x118, 0xF, 0xF, true);
    x += (unsigned)__builtin_amdgcn_update_dpp(0, (int)x, 0x142, 0xA, 0xF, true);
    x += (unsigned)__builtin_amdgcn_update_dpp(0, (int)x, 0x143, 0xC, 0xF, true);
    return x;
}
__device__ __forceinline__ int cell_of(float x, float y, float z) {
    int cx = (int)floorf((x - GLO) * INVH);
    int cy = (int)floorf((y - GLO) * INVH);
    int cz = (int)floorf((z - GLO) * INVH);
    cx = min(max(cx, 0), GDIM - 1);
    cy = min(max(cy, 0), GDIM - 1);
    cz = min(max(cz, 0), GDIM - 1);
    return (cz * GDIM + cy) * GDIM + cx;
}

// ---------------------------------------------------------------------------
// Fused: blocks 0..63 = grid count (atomics); blocks 64..319 = prep GEMM
//   prep: v_p = x_p@(W1a-W1b)+b1 -> vout(==d_out) ; u_p = x_p@W1b -> ubuf bf16
// ---------------------------------------------------------------------------
__global__ __launch_bounds__(256) void count_prep_kernel(const float* __restrict__ pos,
                                                         int* __restrict__ counts,
                                                         const float* __restrict__ x,
                                                         const float* __restrict__ W1,
                                                         const float* __restrict__ b1,
                                                         float* __restrict__ vout,
                                                         unsigned short* __restrict__ ubuf) {
    __shared__ unsigned short Wct[128 * 72];
    __shared__ unsigned short Abuf[64 * 72];
    __shared__ float Wraw[128 * 64];

    const int t = threadIdx.x;
    if (blockIdx.x < 64) {
        const int i = blockIdx.x * 256 + t;
        atomicAdd(&counts[cell_of(pos[i * 3], pos[i * 3 + 1], pos[i * 3 + 2])], 1);
        return;
    }
    const int bid  = blockIdx.x - 64;
    const int lane = t & 63;
    const int w    = t >> 6;

    {
        const float4* W1v = (const float4*)W1;
        float4* Wr4 = (float4*)Wraw;
#pragma unroll
        for (int i = 0; i < 8; ++i) Wr4[i * 256 + t] = W1v[i * 256 + t];
    }
    __syncthreads();
    {
        const int n = t & 127;
        const int ks = (t >> 7) * 32;
#pragma unroll
        for (int i = 0; i < 32; ++i) {
            const int k = ks + i;
            float val;
            if (n < 64) val = Wraw[k * 64 + n] - Wraw[(64 + k) * 64 + n];
            else        val = Wraw[(64 + k) * 64 + (n - 64)];
            Wct[n * 72 + k] = f2bf(val);
        }
    }
    {
        const int col = t & 63;
#pragma unroll
        for (int i = 0; i < 16; ++i) {
            const int r2 = (t >> 6) + 4 * i;
            const int gp = bid * 64 + r2;
            Abuf[r2 * 72 + col] = f2bf(x[(size_t)gp * CH + col]);
        }
    }
    __syncthreads();

    const int m16 = lane & 15;
    const int q   = lane >> 4;

    floatx4 acc[8];
#pragma unroll
    for (int nt = 0; nt < 8; ++nt) acc[nt] = (floatx4){0.f, 0.f, 0.f, 0.f};

#pragma unroll
    for (int kk = 0; kk < 64; kk += 32) {
        const short8 a = *(const short8*)(Abuf + (w * 16 + m16) * 72 + kk + q * 8);
#pragma unroll
        for (int nt = 0; nt < 8; ++nt) {
            const short8 b = *(const short8*)(Wct + (nt * 16 + m16) * 72 + kk + q * 8);
            acc[nt] = __builtin_amdgcn_mfma_f32_16x16x32_bf16(a, b, acc[nt], 0, 0, 0);
        }
    }

#pragma unroll
    for (int nt = 0; nt < 8; ++nt) {
        const int n = nt * 16 + m16;
#pragma unroll
        for (int r = 0; r < 4; ++r) {
            const int gp = bid * 64 + w * 16 + q * 4 + r;
            if (n < 64) vout[(size_t)gp * CH + n] = acc[nt][r] + b1[n];
            else        ubuf[(size_t)gp * CH + (n - 64)] = f2bf(acc[nt][r]);
        }
    }
}

// starts has GCELLS+1 entries; starts[GCELLS] = NPTS sentinel (run ends).
__global__ __launch_bounds__(1024) void scan_kernel(const int* __restrict__ counts,
                                                    int* __restrict__ starts,
                                                    int* __restrict__ cursor) {
    __shared__ int lds[1024];
    const int t = threadIdx.x;
    int4 v[8];
    const int4* c4 = (const int4*)counts + t * 8;
#pragma unroll
    for (int i = 0; i < 8; ++i) v[i] = c4[i];
    int sum = 0;
#pragma unroll
    for (int i = 0; i < 8; ++i) sum += v[i].x + v[i].y + v[i].z + v[i].w;
    lds[t] = sum;
    __syncthreads();
    for (int off = 1; off < 1024; off <<= 1) {
        int x = 0;
        if (t >= off) x = lds[t - off];
        __syncthreads();
        lds[t] += x;
        __syncthreads();
    }
    int pre = (t == 0) ? 0 : lds[t - 1];
    int4* s4 = (int4*)starts + t * 8;
    int4* u4 = (int4*)cursor + t * 8;
#pragma unroll
    for (int i = 0; i < 8; ++i) {
        int4 o;
        o.x = pre; pre += v[i].x;
        o.y = pre; pre += v[i].y;
        o.z = pre; pre += v[i].z;
        o.w = pre; pre += v[i].w;
        s4[i] = o;
        u4[i] = o;
    }
    if (t == 1023) starts[GCELLS] = pre;   // == NPTS
}

__global__ __launch_bounds__(256) void grid_scatter_kernel(const float* __restrict__ pos,
                                                           int* __restrict__ cursor,
                                                           float4* __restrict__ spos,
                                                           unsigned short* __restrict__ sidx) {
    const int i = blockIdx.x * 256 + threadIdx.x;
    const float a = pos[i * 3], b = pos[i * 3 + 1], c = pos[i * 3 + 2];
    const int dst = atomicAdd(&cursor[cell_of(a, b, c)], 1);
    spos[dst] = make_float4(a, b, c, a * a + b * b + c * c);  // same sq expr as query side
    sidx[dst] = (unsigned short)i;
}

// ---------------------------------------------------------------------------
// Grid KNN, run-compacted, append-and-flush selection. 1 wave per SORTED
// query (blockIdx = sorted index; query data from spos/sidx).
// Distance = ref formula d = fmaf(-2, dot, sq_i + sq_j) (identical R10).
// ---------------------------------------------------------------------------
#define SENT 0xFF800000FFFFFFFFULL   // key(+inf) | idx-all-ones
#define NB 4

__global__ __launch_bounds__(64) void knn_grid_kernel(const float4* __restrict__ spos,
                                                      const unsigned short* __restrict__ sidx,
                                                      const int* __restrict__ starts,
                                                      unsigned short* __restrict__ knn_out) {
    __shared__ int lds_ex[64];
    __shared__ int lds_st[64];
    __shared__ unsigned long long buf[64];
    const int lane = threadIdx.x;
    const int sq   = blockIdx.x;

    const float4 qv = spos[sq];
    const float qx = qv.x, qy = qv.y, qz = qv.z, sqi = qv.w;
    const int qrow = (int)sidx[sq];   // original index (output row)
    const int cix = min(max((int)floorf((qx - GLO) * INVH), 0), GDIM - 1);
    const int ciy = min(max((int)floorf((qy - GLO) * INVH), 0), GDIM - 1);
    const int ciz = min(max((int)floorf((qz - GLO) * INVH), 0), GDIM - 1);

    unsigned long long list = SENT;
    float tau = __uint_as_float(0x7F800000u);   // +INF
    bool first = true;
    int nbuf = 0;

    // exact merge of buffered candidates into the running top-16
    auto do_flush = [&]() {
        unsigned long long ck = (lane < nbuf) ? buf[lane] : SENT;
        // 64-lane bitonic sort ascending (same network as warm start)
#pragma unroll
        for (int k = 2; k <= 64; k <<= 1) {
#pragma unroll
            for (int jj = k >> 1; jj >= 1; jj >>= 1) {
                const unsigned long long o = __shfl_xor(ck, jj);
                const bool takeMin = (((lane & k) == 0) == ((lane & jj) == 0));
                const unsigned long long mn = (ck < o) ? ck : o;
                const unsigned long long mx = (ck < o) ? o : ck;
                ck = takeMin ? mn : mx;
            }
        }
        // lanes 0..15: old list (asc); lanes 16..31: buffer top16 desc -> bitonic
        const unsigned long long cv = __shfl(ck, 31 - lane);
        unsigned long long m = SENT;
        if (lane < 16) m = list;
        else if (lane < 32) m = cv;
        // bitonic merge-32 ascending
#pragma unroll
        for (int jj = 16; jj >= 1; jj >>= 1) {
            const unsigned long long o = __shfl_xor(m, jj);
            const unsigned long long mn = (m < o) ? m : o;
            const unsigned long long mx = (m < o) ? o : m;
            m = ((lane & jj) == 0) ? mn : mx;
        }
        list = m;   // lanes 0..15 = new sorted top-16
        const unsigned thi = (unsigned)__builtin_amdgcn_readlane(
            (int)(unsigned)(list >> 32), 15);
        const unsigned fb = (thi >= 0x80000000u) ? (thi & 0x7FFFFFFFu) : ~thi;
        tau = __uint_as_float(fb);
        nbuf = 0;
    };

    int pax = 1, pbx = 0, pay = 1, pby = 0, paz = 1, pbz = 0;  // empty prev cube

    for (int s = 1; s < GDIM + 1; ++s) {
        const int ax = max(cix - s, 0), bx = min(cix + s, GDIM - 1);
        const int ay = max(ciy - s, 0), by = min(ciy + s, GDIM - 1);
        const int az = max(ciz - s, 0), bz = min(ciz + s, GDIM - 1);
        const int dy = by - ay + 1, dz = bz - az + 1;
        const int npair = dy * dz;
        const float invdy = 1.0f / (float)dy;

        for (int pb = 0; pb < npair; pb += 64) {
            const int pair = pb + lane;
            int stA = 0, lenA = 0, stB = 0, lenB = 0;
            if (pair < npair) {
                const int czo = (int)(((float)pair + 0.5f) * invdy);
                const int cyo = pair - czo * dy;
                const int cy = ay + cyo, cz = az + czo;
                const int rowb = (cz * GDIM + cy) * GDIM;
                const bool inner = cy >= pay && cy <= pby && cz >= paz && cz <= pbz;
                const int bA = inner ? (pax - 1) : bx;
                if (bA >= ax) {
                    stA  = starts[rowb + ax];
                    lenA = starts[rowb + bA + 1] - stA;
                }
                if (inner) {
                    const int aB = pbx + 1;
                    if (bx >= aB) {
                        stB  = starts[rowb + aB];
                        lenB = starts[rowb + bx + 1] - stB;
                    }
                }
            }
#pragma unroll
            for (int setsel = 0; setsel < 2; ++setsel) {
                const int st  = setsel ? stB  : stA;
                const int len = setsel ? lenB : lenA;
                if (__ballot(len > 0) == 0ULL) continue;
                const unsigned pfx = wave_iscan((unsigned)len);  // DPP scan
                const int T = __builtin_amdgcn_readlane((int)pfx, 63);
                lds_ex[lane] = (int)pfx - len;
                lds_st[lane] = st;

                for (int b0 = 0; b0 < T; b0 += 64 * NB) {
                    float4 pts[NB];
                    int    jor[NB];
                    bool   act[NB];
                    bool   live[NB];
#pragma unroll
                    for (int nb = 0; nb < NB; ++nb) {
                        const int bb = b0 + nb * 64;
                        live[nb] = bb < T;
                        act[nb] = false;
                        if (live[nb]) {
                            const int p = bb + lane;
                            int j = 0;
#pragma unroll
                            for (int stp = 32; stp >= 1; stp >>= 1) {
                                const int m = j + stp;
                                if (lds_ex[m] <= p) j = m;
                            }
                            int idx = lds_st[j] + (p - lds_ex[j]);
                            idx = min(idx, NPTS - 1);
                            act[nb] = p < T;
                            pts[nb] = spos[idx];
                            jor[nb] = (int)sidx[idx];
                        }
                    }
#pragma unroll
                    for (int nb = 0; nb < NB; ++nb) {
                        if (!live[nb]) continue;
                        // reference-formula distance (identical to R10)
                        const float dot = fmaf(qx, pts[nb].x,
                                               fmaf(qy, pts[nb].y, qz * pts[nb].z));
                        const float d = fmaf(-2.0f, dot, sqi + pts[nb].w);

                        if (first) {
                            first = false;
                            unsigned kd = __float_as_uint(d);
                            kd = ((int)kd < 0) ? ~kd : (kd | 0x80000000u);
                            unsigned long long key =
                                (((unsigned long long)kd) << 32) | (unsigned)jor[nb];
                            if (!(act[nb] && jor[nb] != qrow)) key = SENT;
                            // 64-lane bitonic warm start
#pragma unroll
                            for (int k = 2; k <= 64; k <<= 1) {
#pragma unroll
                                for (int jj = k >> 1; jj >= 1; jj >>= 1) {
                                    const unsigned long long o = __shfl_xor(key, jj);
                                    const bool takeMin =
                                        (((lane & k) == 0) == ((lane & jj) == 0));
                                    const unsigned long long mn = (key < o) ? key : o;
                                    const unsigned long long mx = (key < o) ? o : key;
                                    key = takeMin ? mn : mx;
                                }
                            }
                            list = key;
                            const unsigned thi = (unsigned)__builtin_amdgcn_readlane(
                                (int)(unsigned)(list >> 32), 15);
                            const unsigned fb =
                                (thi >= 0x80000000u) ? (thi & 0x7FFFFFFFu) : ~thi;
                            tau = __uint_as_float(fb);
                            continue;
                        }

                        const bool cand = act[nb] && (jor[nb] != qrow) && (d <= tau);
                        const unsigned long long mask = __ballot(cand);
                        if (mask) {
                            const int cnt = __popcll(mask);
                            if (nbuf + cnt > 64) do_flush();   // wave-uniform
                            if (cand) {
                                unsigned kd = __float_as_uint(d);
                                kd = ((int)kd < 0) ? ~kd : (kd | 0x80000000u);
                                const unsigned long long key =
                                    (((unsigned long long)kd) << 32) | (unsigned)jor[nb];
                                const int rank =
                                    __popcll(mask & ((1ULL << lane) - 1ULL));
                                buf[nbuf + rank] = key;
                            }
                            nbuf += cnt;
                        }
                    }
                }
            }
        }

        if (nbuf) do_flush();   // tighten tau before the termination test

        // termination: min geometric distance from q to unprocessed region,
        // with 1e-4 margin for ref-formula vs geometric rounding skew.
        const float BIG = 1e30f;
        float dout = BIG;
        if (ax > 0)        dout = fminf(dout, qx - (GLO + ax * GH));
        if (bx < GDIM - 1) dout = fminf(dout, (GLO + (bx + 1) * GH) - qx);
        if (ay > 0)        dout = fminf(dout, qy - (GLO + ay * GH));
        if (by < GDIM - 1) dout = fminf(dout, (GLO + (by + 1) * GH) - qy);
        if (az > 0)        dout = fminf(dout, qz - (GLO + az * GH));
        if (bz < GDIM - 1) dout = fminf(dout, (GLO + (bz + 1) * GH) - qz);
        if (dout * dout > tau + 1e-4f) break;
        if (ax == 0 && bx == GDIM - 1 && ay == 0 && by == GDIM - 1 &&
            az == 0 && bz == GDIM - 1) break;
        pax = ax; pbx = bx; pay = ay; pby = by; paz = az; pbz = bz;
    }

    if (lane < 16)
        knn_out[qrow * 16 + lane] = (unsigned short)(list & 0xFFFFULL);
}

// ---------------------------------------------------------------------------
// edge: block = 8 points (128 edge rows). h = relu(v_i + u_j) staged bf16 in
// LDS; GEMM2 (128x64)@(64x64) via MFMA; max over each point's 16 rows; +b2.
// ---------------------------------------------------------------------------
__global__ __launch_bounds__(256) void edge_kernel(const unsigned short* __restrict__ ubuf,
                                                   const float* __restrict__ W2,
                                                   const float* __restrict__ b2,
                                                   const unsigned short* __restrict__ knn,
                                                   float* __restrict__ out) {
    __shared__ unsigned short h[128 * 72];
    __shared__ unsigned short W2t[64 * 72];

    const int t    = threadIdx.x;
    const int lane = t & 63;
    const int w    = t >> 6;

    {
        const int n = t & 63;
        const int kb = (t >> 6) * 16;
#pragma unroll
        for (int i = 0; i < 16; ++i) {
            const int k = kb + i;
            W2t[n * 72 + k] = f2bf(W2[k * 64 + n]);
        }
    }
    {
        const int k = t >> 4;
        const int c = t & 15;
#pragma unroll
        for (int i = 0; i < 8; ++i) {
            const int gn = blockIdx.x * 8 + i;
            const int gj = (int)knn[gn * 16 + k];
            const float4  vv = ((const float4*)(out + (size_t)gn * CH))[c];
            const ushort4 uu = ((const ushort4*)(ubuf + (size_t)gj * CH))[c];
            ushort4 hv;
            hv.x = f2bf(fmaxf(vv.x + bf2f(uu.x), 0.f));
            hv.y = f2bf(fmaxf(vv.y + bf2f(uu.y), 0.f));
            hv.z = f2bf(fmaxf(vv.z + bf2f(uu.z), 0.f));
            hv.w = f2bf(fmaxf(vv.w + bf2f(uu.w), 0.f));
            const int r2 = i * 16 + k;
            *(ushort4*)(h + r2 * 72 + c * 4) = hv;
        }
    }
    __syncthreads();

    const int m16 = lane & 15;
    const int q   = lane >> 4;

    floatx4 acc[2][4];
#pragma unroll
    for (int i = 0; i < 2; ++i)
#pragma unroll
        for (int nt = 0; nt < 4; ++nt) acc[i][nt] = (floatx4){0.f, 0.f, 0.f, 0.f};

#pragma unroll
    for (int kk = 0; kk < 64; kk += 32) {
        const short8 a0 = *(const short8*)(h + ((w * 2 + 0) * 16 + m16) * 72 + kk + q * 8);
        const short8 a1 = *(const short8*)(h + ((w * 2 + 1) * 16 + m16) * 72 + kk + q * 8);
#pragma unroll
        for (int nt = 0; nt < 4; ++nt) {
            const short8 b = *(const short8*)(W2t + (nt * 16 + m16) * 72 + kk + q * 8);
            acc[0][nt] = __builtin_amdgcn_mfma_f32_16x16x32_bf16(a0, b, acc[0][nt], 0, 0, 0);
            acc[1][nt] = __builtin_amdgcn_mfma_f32_16x16x32_bf16(a1, b, acc[1][nt], 0, 0, 0);
        }
    }

#pragma unroll
    for (int i = 0; i < 2; ++i) {
        const int mt = w * 2 + i;
        const int gn = blockIdx.x * 8 + mt;
#pragma unroll
        for (int nt = 0; nt < 4; ++nt) {
            float m0 = fmaxf(fmaxf(acc[i][nt][0], acc[i][nt][1]),
                             fmaxf(acc[i][nt][2], acc[i][nt][3]));
            m0 = fmaxf(m0, __shfl_xor(m0, 16));
            m0 = fmaxf(m0, __shfl_xor(m0, 32));
            if (lane < 16)
                out[(size_t)gn * CH + nt * 16 + lane] = m0 + b2[nt * 16 + lane];
        }
    }
}

extern "C" void kernel_launch(void* const* d_in, const int* in_sizes, int n_in,
                              void* d_out, int out_size, void* d_ws, size_t ws_size,
                              hipStream_t stream) {
    const float* x   = (const float*)d_in[0];
    const float* pos = (const float*)d_in[1];
    const float* W1  = (const float*)d_in[2];
    const float* b1  = (const float*)d_in[3];
    const float* W2  = (const float*)d_in[4];
    const float* b2  = (const float*)d_in[5];
    float* out = (float*)d_out;

    char* ws = (char*)d_ws;
    unsigned short* knn  = (unsigned short*)ws;                    // 512 KB @ 0
    unsigned short* ubuf = (unsigned short*)(ws + 524288);         // 2 MB
    int*    counts = (int*)(ws + 2621440);                         // 128 KB
    int*    starts = (int*)(ws + 2752512);                         // 128 KB + sentinel
    int*    cursor = (int*)(ws + 2883600);                         // 128 KB
    float4* spos   = (float4*)(ws + 3014672);                      // 256 KB
    unsigned short* sidx = (unsigned short*)(ws + 3276816);        // 32 KB

    hipMemsetAsync(counts, 0, GCELLS * sizeof(int), stream);
    count_prep_kernel<<<320, 256, 0, stream>>>(pos, counts, x, W1, b1, out, ubuf);
    scan_kernel<<<1, 1024, 0, stream>>>(counts, starts, cursor);
    grid_scatter_kernel<<<NPTS / 256, 256, 0, stream>>>(pos, cursor, spos, sidx);
    knn_grid_kernel<<<NPTS, 64, 0, stream>>>(spos, sidx, starts, knn);
    edge_kernel<<<NPTS / 8, 256, 0, stream>>>(ubuf, W2, b2, knn, out);
}